// Round 13
// baseline (1186.934 us; speedup 1.0000x reference)
//
#include <hip/hip_runtime.h>
#include <hip/hip_bf16.h>
#include <stdint.h>

typedef __hip_bfloat16 bf16;
typedef __attribute__((ext_vector_type(8))) short short8;
typedef __attribute__((ext_vector_type(4))) float f32x4;

__device__ __forceinline__ bf16 f2b(float x) { return __float2bfloat16(x); }

#define NW 8

// ---- LDS map (bytes) ----
#define A0_OFF 0
#define X_OFF  77440
#define A1_OFF 77440
#define A2_OFF 0
#define Z_OFF  57024
#define BB_OFF 114048      // 3 x 16384
#define BS_OFF 147840      // 3 x 5120
#define YF_OFF 0
#define SMEM_SZ 163200

__device__ __forceinline__ void gload_lds16(const void* g, char* l) {
    __builtin_amdgcn_global_load_lds(
        (const __attribute__((address_space(1))) unsigned int*)g,
        (__attribute__((address_space(3))) unsigned int*)l, 16, 0, 0);
}

// Pin the residual trunk into the AGPR class (frees arch VGPRs; the unified
// file on gfx950 allows VALU access to AGPRs, compiler inserts moves if not).
__device__ __forceinline__ void pin_agpr(f32x4 (&Y)[4][5]) {
#pragma unroll
    for (int mm = 0; mm < 4; ++mm)
#pragma unroll
        for (int n = 0; n < 5; ++n)
            asm volatile("" : "+a"(Y[mm][n][0]), "+a"(Y[mm][n][1]),
                              "+a"(Y[mm][n][2]), "+a"(Y[mm][n][3]));
}

// ---------------------------------------------------------------------------
// Top-k: exact rank, jax tie-break (lower index wins). 32 blocks.
// ---------------------------------------------------------------------------
__global__ __launch_bounds__(1024) void topk_kernel(const float* __restrict__ err,
                                                    float* __restrict__ ref_out,
                                                    int* __restrict__ sel)
{
    __shared__ uint64_t keys[4096];
    const int b = blockIdx.x >> 4, slice = blockIdx.x & 15;
    const float* e = err + b * 4096;
    for (int t = threadIdx.x; t < 4096; t += 1024) {
        uint32_t u = __float_as_uint(e[t]);
        u ^= (u >> 31) ? 0xFFFFFFFFu : 0x80000000u;
        keys[t] = ((uint64_t)u << 32) | (uint32_t)(4095 - t);
    }
    __syncthreads();
    const int cand = slice * 256 + (threadIdx.x >> 2);
    const int part = threadIdx.x & 3;
    const uint64_t mykey = keys[cand];
    int r = 0;
#pragma unroll 8
    for (int j = part * 1024; j < part * 1024 + 1024; ++j)
        r += (keys[j] > mykey) ? 1 : 0;
    r += __shfl_xor(r, 1);
    r += __shfl_xor(r, 2);
    if (part == 0) {
        bool s = (r < 512);
        if (s) sel[b * 512 + r] = cand;
        ref_out[b * 4096 + cand] = (s && e[cand] > 0.f) ? 1.f : 0.f;
    }
}

// ---------------------------------------------------------------------------
// Weight prepack: Wf = [l][tap][kb][n][lane][8] bf16 (l==0 kb=0 only),
// co=n*16+(lane&15), k=kb*32+(lane>>4)*8+i, ZERO for k>=C_in.
// BN inv-scale FOLDED into weights; beta stored separately (acc-init).
// ---------------------------------------------------------------------------
__global__ void wt_kernel(const float* __restrict__ w0, const float* __restrict__ wpre,
                          const float* __restrict__ wpost, const float* __restrict__ w_last,
                          const float* __restrict__ bn0, const float* __restrict__ bn_pre,
                          const float* __restrict__ bn_post,
                          bf16* __restrict__ Wf, float* __restrict__ wlastT,
                          float* __restrict__ bnbeta)
{
    int t = blockIdx.x * blockDim.x + threadIdx.x;
    if (t < 714240) {
        int l, tap, kb, rem;
        if (t < 23040) { l = 0; tap = t / 2560; kb = 0; rem = t % 2560; }
        else {
            int t2 = t - 23040;
            l = 1 + t2 / 69120;
            int r0 = t2 % 69120;
            tap = r0 / 7680;
            int r1 = r0 % 7680;
            kb = r1 / 2560; rem = r1 % 2560;
        }
        int n = rem / 512, r2 = rem % 512, lane = r2 / 8, i = r2 % 8;
        int co = n * 16 + (lane & 15);
        int k  = kb * 32 + (lane >> 4) * 8 + i;
        float v = 0.f;
        if (l == 0)      { if (k < 31) v = w0[(co * 31 + k) * 9 + tap]; }
        else if (l <= 3) { if (k < 80) v = wpre[(((l - 1) * 80 + co) * 80 + k) * 9 + tap]; }
        else             { if (k < 80) v = wpost[(((l - 4) * 80 + co) * 80 + k) * 9 + tap]; }
        const float* src = (l == 0) ? bn0 : (l <= 3 ? bn_pre + (l - 1) * 320
                                                    : bn_post + (l - 4) * 320);
        float inv = src[co] * rsqrtf(src[240 + co] + 1e-5f);
        Wf[t] = f2b(v * inv);
    } else if (t < 714960) {
        int i = t - 714240; int tap = i / 80, ci = i % 80;
        wlastT[tap * 80 + ci] = w_last[ci * 9 + tap];
    } else if (t < 715840) {
        int i = t - 714960; int l = i / 80, co = i % 80;
        const float* src = (l == 0) ? bn0 : (l <= 3 ? bn_pre + (l - 1) * 320
                                                    : bn_post + (l - 4) * 320);
        float inv = src[co] * rsqrtf(src[240 + co] + 1e-5f);
        bnbeta[i] = src[80 + co] - src[160 + co] * inv;
    }
}

// ---------------------------------------------------------------------------
__global__ void copy_kernel(const uint4* __restrict__ src, uint4* __restrict__ dst, int n)
{
    int t = blockIdx.x * blockDim.x + threadIdx.x;
    if (t < n) dst[t] = src[t];
}

// ---------------------------------------------------------------------------
// Small VALID conv (conv0/pre1/pre2): 8 waves x 2x2 mtiles x 5 n — the
// R11-proven form. Counted 3-slot vmcnt pipeline.
// ---------------------------------------------------------------------------
template <int NIN, int NOUT, int KB, int ISTR, int OSTR>
__device__ __forceinline__ void conv_small(char* sm, int inBase, int outBase,
                                           const char* __restrict__ Wl,
                                           const float* __restrict__ bnl)
{
    const int tid = threadIdx.x;
    const int wv = tid >> 6, lane = tid & 63;
    const int r = lane & 15, kg = lane >> 4;
    constexpr int NPIX = NOUT * NOUT;
    constexpr int NMT = (NPIX + 15) / 16;
    constexpr int NSTEP = 9 * KB;

    int aA[2][2];
    bool act[2][2];
#pragma unroll
    for (int pp = 0; pp < 2; ++pp)
#pragma unroll
        for (int mm = 0; mm < 2; ++mm) {
            int mt = (wv + pp * NW) * 2 + mm;
            int pix = mt * 16 + r;
            act[pp][mm] = (mt < NMT);
            int cp = pix < NPIX ? pix : NPIX - 1;
            aA[pp][mm] = inBase + ((cp / NOUT) * NIN + cp % NOUT) * ISTR + kg * 16;
        }

    float betb[5];
#pragma unroll
    for (int n = 0; n < 5; ++n) betb[n] = bnl[n * 16 + r];
    asm volatile("" :: "v"(betb[0]), "v"(betb[1]), "v"(betb[2]),
                       "v"(betb[3]), "v"(betb[4]));

    f32x4 acc[2][2][5];
#pragma unroll
    for (int pp = 0; pp < 2; ++pp)
#pragma unroll
        for (int mm = 0; mm < 2; ++mm)
#pragma unroll
            for (int n = 0; n < 5; ++n) {
                f32x4 bi = {betb[n], betb[n], betb[n], betb[n]};
                acc[pp][mm][n] = bi;
            }

    auto stage = [&](int step) {
        if (tid < 320)
            gload_lds16(Wl + step * 5120 + tid * 16,
                        sm + BS_OFF + (step % 3) * 5120 + tid * 16);
    };

    asm volatile("s_waitcnt vmcnt(0)" ::: "memory");
    stage(0); stage(1);
    asm volatile("s_waitcnt vmcnt(1) lgkmcnt(0)" ::: "memory");
    __builtin_amdgcn_s_barrier();

#pragma unroll
    for (int s = 0; s < NSTEP; ++s) {
        if (s + 2 < NSTEP) stage(s + 2);
        const int tap = s / KB, kb = s % KB;
        const int dtap = (tap / 3) * NIN + (tap % 3);
        const int sb = BS_OFF + (s % 3) * 5120;
        short8 bf[5];
#pragma unroll
        for (int n = 0; n < 5; ++n)
            bf[n] = *(const short8*)(sm + sb + n * 1024 + lane * 16);
#pragma unroll
        for (int pp = 0; pp < 2; ++pp)
#pragma unroll
            for (int mm = 0; mm < 2; ++mm) {
                if (!act[pp][mm]) continue;   // wave-uniform skip
                short8 af = *(const short8*)(sm + aA[pp][mm] + dtap * ISTR + kb * 64);
#pragma unroll
                for (int n = 0; n < 5; ++n)
                    acc[pp][mm][n] = __builtin_amdgcn_mfma_f32_16x16x32_bf16(
                        af, bf[n], acc[pp][mm][n], 0, 0, 0);
            }
        if (s + 2 < NSTEP)
            asm volatile("s_waitcnt vmcnt(1) lgkmcnt(0)" ::: "memory");
        else
            asm volatile("s_waitcnt vmcnt(0) lgkmcnt(0)" ::: "memory");
        __builtin_amdgcn_s_barrier();
    }

#pragma unroll
    for (int pp = 0; pp < 2; ++pp)
#pragma unroll
        for (int mm = 0; mm < 2; ++mm) {
            int mt = (wv + pp * NW) * 2 + mm;
            if (mt < NMT) {
#pragma unroll
                for (int n = 0; n < 5; ++n) {
                    int co = n * 16 + r;
#pragma unroll
                    for (int j = 0; j < 4; ++j) {
                        int pix = mt * 16 + kg * 4 + j;
                        if (pix < NPIX) {
                            float o = fmaxf(acc[pp][mm][n][j], 0.f);
                            *(bf16*)(sm + outBase + pix * OSTR + co * 2) = f2b(o);
                        }
                    }
                }
            }
        }
}

// ---------------------------------------------------------------------------
// Big layer (pre3 VALID 18->16 / post SAME on Z ring): waves 0-3 compute
// 4 rows x 5 n (halves B redundancy); waves 4-7 stage+barrier. Yreg lives in
// the AGPR class (pin_agpr) so the arch budget holds ~70 regs.
// MODE 1: Yreg = relu(acc) + Z store; MODE 2: Yreg += relu(acc) (+Z store).
// ---------------------------------------------------------------------------
template <int MODE, int STOREZ>
__device__ __forceinline__ void conv_big(char* sm, int inBase,
                                         const char* __restrict__ Wl,
                                         const float* __restrict__ bnl,
                                         f32x4 (&Yreg)[4][5])
{
    const int tid = threadIdx.x;
    const int wv = tid >> 6, lane = tid & 63;
    const int r = lane & 15, kg = lane >> 4;
    const bool cw = (wv < 4);

    if (MODE == 2 && cw) pin_agpr(Yreg);   // keep trunk in AGPRs across loop

    float betb[5];
#pragma unroll
    for (int n = 0; n < 5; ++n) betb[n] = bnl[n * 16 + r];
    asm volatile("" :: "v"(betb[0]), "v"(betb[1]), "v"(betb[2]),
                       "v"(betb[3]), "v"(betb[4]));

    f32x4 acc[4][5];
#pragma unroll
    for (int mm = 0; mm < 4; ++mm)
#pragma unroll
        for (int n = 0; n < 5; ++n) {
            f32x4 bi = {betb[n], betb[n], betb[n], betb[n]};
            acc[mm][n] = bi;
        }

    int aBase[4];
#pragma unroll
    for (int mm = 0; mm < 4; ++mm)
        aBase[mm] = inBase + (((wv & 3) * 4 + mm) * 18 + r) * 176 + kg * 16;

    auto stage = [&](int step) {
        const char* src = Wl + step * 15360;
        char* dst = sm + BB_OFF + (step % 3) * 16384;
        gload_lds16(src + tid * 16, dst + tid * 16);
        gload_lds16(src + 8192 + tid * 16, dst + 8192 + tid * 16);
    };

    asm volatile("s_waitcnt vmcnt(0)" ::: "memory");
    stage(0); stage(1);
    asm volatile("s_waitcnt vmcnt(2) lgkmcnt(0)" ::: "memory");
    __builtin_amdgcn_s_barrier();

#pragma unroll
    for (int s = 0; s < 9; ++s) {
        if (s + 2 < 9) stage(s + 2);
        if (cw) {
            const int dt = ((s / 3) * 18 + (s % 3)) * 176;
            const int sb = BB_OFF + (s % 3) * 16384;
#pragma unroll
            for (int kb = 0; kb < 3; ++kb) {
                short8 bf[5];
#pragma unroll
                for (int n = 0; n < 5; ++n)
                    bf[n] = *(const short8*)(sm + sb + kb * 5120 + n * 1024 + lane * 16);
#pragma unroll
                for (int mm = 0; mm < 4; ++mm) {
                    short8 af = *(const short8*)(sm + aBase[mm] + dt + kb * 64);
#pragma unroll
                    for (int n = 0; n < 5; ++n)
                        acc[mm][n] = __builtin_amdgcn_mfma_f32_16x16x32_bf16(
                            af, bf[n], acc[mm][n], 0, 0, 0);
                }
            }
        }
        if (s + 2 < 9)
            asm volatile("s_waitcnt vmcnt(2) lgkmcnt(0)" ::: "memory");
        else
            asm volatile("s_waitcnt vmcnt(0) lgkmcnt(0)" ::: "memory");
        __builtin_amdgcn_s_barrier();
    }

    if (cw) {
#pragma unroll
        for (int mm = 0; mm < 4; ++mm) {
            int y = (wv & 3) * 4 + mm;
#pragma unroll
            for (int n = 0; n < 5; ++n) {
                int co = n * 16 + r;
#pragma unroll
                for (int j = 0; j < 4; ++j) {
                    int x = kg * 4 + j;
                    float o = fmaxf(acc[mm][n][j], 0.f);
                    if (MODE == 1) {
                        Yreg[mm][n][j] = o;
                        *(bf16*)(sm + Z_OFF + ((y + 1) * 18 + x + 1) * 176 + co * 2) = f2b(o);
                    } else {
                        float nv = Yreg[mm][n][j] + o;
                        Yreg[mm][n][j] = nv;
                        if (STOREZ)
                            *(bf16*)(sm + Z_OFF + ((y + 1) * 18 + x + 1) * 176 + co * 2) = f2b(nv);
                    }
                }
            }
        }
        pin_agpr(Yreg);   // keep trunk pinned for the next layer
    }
}

// ---------------------------------------------------------------------------
__global__ __launch_bounds__(512, 2) void refine_kernel(
    const int* __restrict__ sel,
    const float* __restrict__ hid, const float* __restrict__ pha,
    const char* __restrict__ Wf, const float* __restrict__ wlastT,
    const float* __restrict__ bnbeta, float* __restrict__ out)
{
    __shared__ __align__(16) char sm[SMEM_SZ];
    const int tid = threadIdx.x;
    const int p = blockIdx.x;
    const int e = sel[p];
    const int b = p >> 9;
    const int pi = e >> 6, pj = e & 63;

    // zero-fill LDS once (pad bytes / stale-data safety)
    {
        uint4 z4 = {0u, 0u, 0u, 0u};
        uint4* z = (uint4*)sm;
        for (int t = tid; t < SMEM_SZ / 16; t += 512) z[t] = z4;
    }
    __syncthreads();

    // gather X[576 pix][ch31] bf16, 80B rows
    const int r0 = pi * 16 - 4, c0 = pj * 16 - 4;
    for (int t = tid; t < 32 * 576; t += 512) {
        int c = t / 576, pix = t - c * 576;
        int gr = r0 + pix / 24, gc = c0 + pix % 24;
        float v = 0.f;
        if (c < 31 && (unsigned)gr < 1024u && (unsigned)gc < 1024u)
            v = (c < 30) ? hid[((b * 30 + c) * 1024 + gr) * 1024 + gc]
                         : pha[(b * 1024 + gr) * 1024 + gc];
        *(bf16*)(sm + X_OFF + pix * 80 + c * 2) = f2b(v);
    }
    // conv0 prologue (vmcnt(0)+lgkmcnt(0)+barrier) covers the gather.

    conv_small<24, 22, 1,  80, 160>(sm, X_OFF,  A0_OFF, Wf,          bnbeta);
    conv_small<22, 20, 3, 160, 176>(sm, A0_OFF, A1_OFF, Wf + 46080,  bnbeta + 80);
    conv_small<20, 18, 3, 176, 176>(sm, A1_OFF, A2_OFF, Wf + 184320, bnbeta + 160);

    // zero Z-ring border (68 cells x 176B); published by pre3 prologue barrier
    for (int t = tid; t < 68 * 11; t += 512) {
        int cell = t / 11, part = t % 11;
        int i, j;
        if (cell < 18)      { i = 0;  j = cell; }
        else if (cell < 36) { i = 17; j = cell - 18; }
        else { int k = cell - 36; i = 1 + (k >> 1); j = (k & 1) ? 17 : 0; }
        *(uint4*)(sm + Z_OFF + (i * 18 + j) * 176 + part * 16) = (uint4){0u, 0u, 0u, 0u};
    }

    f32x4 Yreg[4][5];
    conv_big<1, 1>(sm, A2_OFF, Wf + 322560, bnbeta + 240, Yreg);
#pragma unroll 1
    for (int l = 0; l < 6; ++l)
        conv_big<2, 1>(sm, Z_OFF, Wf + 460800 + l * 138240, bnbeta + 320 + l * 80, Yreg);
    conv_big<2, 0>(sm, Z_OFF, Wf + 460800 + 6 * 138240, bnbeta + 800, Yreg);

    // spill Y trunk (f32, stride 336B) over dead A2/Z region (waves 0-3 own Y)
    {
        const int wv = tid >> 6, lane = tid & 63;
        const int r = lane & 15, kg = lane >> 4;
        if (wv < 4) {
#pragma unroll
            for (int mm = 0; mm < 4; ++mm)
#pragma unroll
                for (int n = 0; n < 5; ++n) {
                    int co = n * 16 + r;
#pragma unroll
                    for (int j = 0; j < 4; ++j) {
                        int pix = (wv * 4 + mm) * 16 + kg * 4 + j;
                        *(float*)(sm + YF_OFF + pix * 336 + co * 4) = Yreg[mm][n][j];
                    }
                }
        }
    }
    __syncthreads();

    // last conv 80->1 SAME; 2 threads per pixel
    {
        int pix = tid >> 1, half = tid & 1;
        int y = pix >> 4, x = pix & 15;
        float accv = 0.f;
        const float* Yb = (const float*)(sm + YF_OFF);
#pragma unroll
        for (int tap = 0; tap < 9; ++tap) {
            int iy = y + tap / 3 - 1, ix = x + tap % 3 - 1;
            if ((unsigned)iy >= 16u || (unsigned)ix >= 16u) continue;
            const float* yp = Yb + (iy * 16 + ix) * 84;
            const float* wp = wlastT + tap * 80;
            for (int c = half * 40; c < half * 40 + 40; c += 4) {
                float4 a  = *(const float4*)(yp + c);
                float4 w4 = *(const float4*)(wp + c);
                accv += a.x * w4.x + a.y * w4.y + a.z * w4.z + a.w * w4.w;
            }
        }
        accv += __shfl_xor(accv, 1);
        if (half == 0)
            out[b * 1048576 + (pi * 16 + y) * 1024 + pj * 16 + x] = accv;
    }
}

// ---------------------------------------------------------------------------
extern "C" void kernel_launch(void* const* d_in, const int* in_sizes, int n_in,
                              void* d_out, int out_size, void* d_ws, size_t ws_size,
                              hipStream_t stream)
{
    (void)in_sizes; (void)n_in; (void)out_size; (void)ws_size;
    const float* pha     = (const float*)d_in[0];
    const float* err     = (const float*)d_in[1];
    const float* hid     = (const float*)d_in[2];
    const float* w0      = (const float*)d_in[3];
    const float* bn0     = (const float*)d_in[4];
    const float* w_pre   = (const float*)d_in[5];
    const float* bn_pre  = (const float*)d_in[6];
    const float* w_post  = (const float*)d_in[7];
    const float* bn_post = (const float*)d_in[8];
    const float* w_last  = (const float*)d_in[9];
    float* out = (float*)d_out;

    char* ws = (char*)d_ws;
    bf16*  Wf     = (bf16*)ws;                 // 714240 bf16 = 1,428,480 B (+1KB stage-overread pad)
    float* wlastT = (float*)(ws + 1429504);    // 720 f32
    float* bnbeta = (float*)(ws + 1432384);    // 880 f32
    int*   sel    = (int*)(ws + 1441792);      // 1024 int

    hipLaunchKernelGGL(wt_kernel, dim3(2797), dim3(256), 0, stream,
                       w0, w_pre, w_post, w_last, bn0, bn_pre, bn_post,
                       Wf, wlastT, bnbeta);
    hipLaunchKernelGGL(topk_kernel, dim3(32), dim3(1024), 0, stream,
                       err, out + 2097152, sel);
    hipLaunchKernelGGL(copy_kernel, dim3(2048), dim3(256), 0, stream,
                       (const uint4*)pha, (uint4*)out, 524288);
    hipLaunchKernelGGL(refine_kernel, dim3(1024), dim3(512), 0, stream,
                       sel, hid, pha, (const char*)Wf, wlastT, bnbeta, out);
}

// Round 14
// 983.448 us; speedup vs baseline: 1.2069x; 1.2069x over previous
//
#include <hip/hip_runtime.h>
#include <hip/hip_bf16.h>
#include <stdint.h>

typedef __hip_bfloat16 bf16;
typedef __attribute__((ext_vector_type(8))) short short8;
typedef __attribute__((ext_vector_type(4))) float f32x4;

__device__ __forceinline__ bf16 f2b(float x) { return __float2bfloat16(x); }

#define NT 256   // threads per block (4 waves)

// ---- LDS map (bytes) ----
#define A0_OFF 0
#define X_OFF  77440
#define A1_OFF 77440
#define A2_OFF 0
#define Z_OFF  57024
#define BB_OFF 114048      // 3 x 16384
#define BS_OFF 147840      // 3 x 5120
#define YF_OFF 0
#define SMEM_SZ 163200

__device__ __forceinline__ void gload_lds16(const void* g, char* l) {
    __builtin_amdgcn_global_load_lds(
        (const __attribute__((address_space(1))) unsigned int*)g,
        (__attribute__((address_space(3))) unsigned int*)l, 16, 0, 0);
}

// ---------------------------------------------------------------------------
// Top-k: exact rank, jax tie-break (lower index wins). 32 blocks.
// ---------------------------------------------------------------------------
__global__ __launch_bounds__(1024) void topk_kernel(const float* __restrict__ err,
                                                    float* __restrict__ ref_out,
                                                    int* __restrict__ sel)
{
    __shared__ uint64_t keys[4096];
    const int b = blockIdx.x >> 4, slice = blockIdx.x & 15;
    const float* e = err + b * 4096;
    for (int t = threadIdx.x; t < 4096; t += 1024) {
        uint32_t u = __float_as_uint(e[t]);
        u ^= (u >> 31) ? 0xFFFFFFFFu : 0x80000000u;
        keys[t] = ((uint64_t)u << 32) | (uint32_t)(4095 - t);
    }
    __syncthreads();
    const int cand = slice * 256 + (threadIdx.x >> 2);
    const int part = threadIdx.x & 3;
    const uint64_t mykey = keys[cand];
    int r = 0;
#pragma unroll 8
    for (int j = part * 1024; j < part * 1024 + 1024; ++j)
        r += (keys[j] > mykey) ? 1 : 0;
    r += __shfl_xor(r, 1);
    r += __shfl_xor(r, 2);
    if (part == 0) {
        bool s = (r < 512);
        if (s) sel[b * 512 + r] = cand;
        ref_out[b * 4096 + cand] = (s && e[cand] > 0.f) ? 1.f : 0.f;
    }
}

// ---------------------------------------------------------------------------
// Weight prepack: Wf = [l][tap][kb][n][lane][8] bf16 (l==0 kb=0 only),
// co=n*16+(lane&15), k=kb*32+(lane>>4)*8+i, ZERO for k>=C_in.
// BN inv-scale FOLDED into weights; beta stored separately (acc-init).
// ---------------------------------------------------------------------------
__global__ void wt_kernel(const float* __restrict__ w0, const float* __restrict__ wpre,
                          const float* __restrict__ wpost, const float* __restrict__ w_last,
                          const float* __restrict__ bn0, const float* __restrict__ bn_pre,
                          const float* __restrict__ bn_post,
                          bf16* __restrict__ Wf, float* __restrict__ wlastT,
                          float* __restrict__ bnbeta)
{
    int t = blockIdx.x * blockDim.x + threadIdx.x;
    if (t < 714240) {
        int l, tap, kb, rem;
        if (t < 23040) { l = 0; tap = t / 2560; kb = 0; rem = t % 2560; }
        else {
            int t2 = t - 23040;
            l = 1 + t2 / 69120;
            int r0 = t2 % 69120;
            tap = r0 / 7680;
            int r1 = r0 % 7680;
            kb = r1 / 2560; rem = r1 % 2560;
        }
        int n = rem / 512, r2 = rem % 512, lane = r2 / 8, i = r2 % 8;
        int co = n * 16 + (lane & 15);
        int k  = kb * 32 + (lane >> 4) * 8 + i;
        float v = 0.f;
        if (l == 0)      { if (k < 31) v = w0[(co * 31 + k) * 9 + tap]; }
        else if (l <= 3) { if (k < 80) v = wpre[(((l - 1) * 80 + co) * 80 + k) * 9 + tap]; }
        else             { if (k < 80) v = wpost[(((l - 4) * 80 + co) * 80 + k) * 9 + tap]; }
        const float* src = (l == 0) ? bn0 : (l <= 3 ? bn_pre + (l - 1) * 320
                                                    : bn_post + (l - 4) * 320);
        float inv = src[co] * rsqrtf(src[240 + co] + 1e-5f);
        Wf[t] = f2b(v * inv);
    } else if (t < 714960) {
        int i = t - 714240; int tap = i / 80, ci = i % 80;
        wlastT[tap * 80 + ci] = w_last[ci * 9 + tap];
    } else if (t < 715840) {
        int i = t - 714960; int l = i / 80, co = i % 80;
        const float* src = (l == 0) ? bn0 : (l <= 3 ? bn_pre + (l - 1) * 320
                                                    : bn_post + (l - 4) * 320);
        float inv = src[co] * rsqrtf(src[240 + co] + 1e-5f);
        bnbeta[i] = src[80 + co] - src[160 + co] * inv;
    }
}

// ---------------------------------------------------------------------------
__global__ void copy_kernel(const uint4* __restrict__ src, uint4* __restrict__ dst, int n)
{
    int t = blockIdx.x * blockDim.x + threadIdx.x;
    if (t < n) dst[t] = src[t];
}

// ---------------------------------------------------------------------------
// Small VALID conv (conv0/pre1/pre2): 4 waves x MTW mtiles x 5 n.
// Counted 3-slot vmcnt pipeline; stage = EXACTLY 2 wave-uniform instructions
// ([0,4096) per-wave-sliced + [4096,5120) redundantly by all waves).
// ---------------------------------------------------------------------------
template <int NIN, int NOUT, int KB, int ISTR, int OSTR, int MTW>
__device__ __forceinline__ void conv_small(char* sm, int inBase, int outBase,
                                           const char* __restrict__ Wl,
                                           const float* __restrict__ bnl)
{
    const int tid = threadIdx.x;
    const int wv = tid >> 6, lane = tid & 63;
    const int r = lane & 15, kg = lane >> 4;
    constexpr int NPIX = NOUT * NOUT;
    constexpr int NMT = (NPIX + 15) / 16;
    constexpr int NSTEP = 9 * KB;

    int aA[MTW];
    bool act[MTW];
#pragma unroll
    for (int q = 0; q < MTW; ++q) {
        int mt = q * 4 + wv;
        int pix = mt * 16 + r;
        act[q] = (mt < NMT);   // wave-uniform
        int cp = pix < NPIX ? pix : NPIX - 1;
        aA[q] = inBase + ((cp / NOUT) * NIN + cp % NOUT) * ISTR + kg * 16;
    }

    float betb[5];
#pragma unroll
    for (int n = 0; n < 5; ++n) betb[n] = bnl[n * 16 + r];
    asm volatile("" :: "v"(betb[0]), "v"(betb[1]), "v"(betb[2]),
                       "v"(betb[3]), "v"(betb[4]));

    f32x4 acc[MTW][5];
#pragma unroll
    for (int q = 0; q < MTW; ++q)
#pragma unroll
        for (int n = 0; n < 5; ++n) {
            f32x4 bi = {betb[n], betb[n], betb[n], betb[n]};
            acc[q][n] = bi;
        }

    auto stage = [&](int step) {
        const char* src = Wl + step * 5120;
        char* dst = sm + BS_OFF + (step % 3) * 5120;
        gload_lds16(src + tid * 16, dst + tid * 16);                       // [0,4096)
        int o2 = 4096 + (tid & 63) * 16;                                   // [4096,5120) x4 redundant
        gload_lds16(src + o2, dst + o2);
    };

    asm volatile("s_waitcnt vmcnt(0)" ::: "memory");
    stage(0); stage(1);
    asm volatile("s_waitcnt vmcnt(2) lgkmcnt(0)" ::: "memory");
    __builtin_amdgcn_s_barrier();

#pragma unroll
    for (int s = 0; s < NSTEP; ++s) {
        if (s + 2 < NSTEP) stage(s + 2);
        const int tap = s / KB, kb = s % KB;
        const int dtap = (tap / 3) * NIN + (tap % 3);
        const int sb = BS_OFF + (s % 3) * 5120;
        short8 bf[5];
#pragma unroll
        for (int n = 0; n < 5; ++n)
            bf[n] = *(const short8*)(sm + sb + n * 1024 + lane * 16);
#pragma unroll
        for (int q = 0; q < MTW; ++q) {
            if (!act[q]) continue;   // wave-uniform skip
            short8 af = *(const short8*)(sm + aA[q] + dtap * ISTR + kb * 64);
#pragma unroll
            for (int n = 0; n < 5; ++n)
                acc[q][n] = __builtin_amdgcn_mfma_f32_16x16x32_bf16(
                    af, bf[n], acc[q][n], 0, 0, 0);
        }
        if (s + 2 < NSTEP)
            asm volatile("s_waitcnt vmcnt(2) lgkmcnt(0)" ::: "memory");
        else
            asm volatile("s_waitcnt vmcnt(0) lgkmcnt(0)" ::: "memory");
        __builtin_amdgcn_s_barrier();
    }

#pragma unroll
    for (int q = 0; q < MTW; ++q) {
        if (act[q]) {
            int mt = q * 4 + wv;
#pragma unroll
            for (int n = 0; n < 5; ++n) {
                int co = n * 16 + r;
#pragma unroll
                for (int j = 0; j < 4; ++j) {
                    int pix = mt * 16 + kg * 4 + j;
                    if (pix < NPIX) {
                        float o = fmaxf(acc[q][n][j], 0.f);
                        *(bf16*)(sm + outBase + pix * OSTR + co * 2) = f2b(o);
                    }
                }
            }
        }
    }
}

// ---------------------------------------------------------------------------
// Big layer (pre3 VALID 18->16 / post SAME on Z ring): 4 waves x 4 rows x 5 n.
// Counted 3-slot pipeline; stage = EXACTLY 4 wave-uniform instructions
// (instr 3 overlaps instr 2's tail redundantly — same data, benign).
// MODE 1: Yreg = relu(acc) + Z store; MODE 2: Yreg += relu(acc) (+Z store).
// ---------------------------------------------------------------------------
template <int MODE, int STOREZ>
__device__ __forceinline__ void conv_big(char* sm, int inBase,
                                         const char* __restrict__ Wl,
                                         const float* __restrict__ bnl,
                                         f32x4 (&Yreg)[4][5])
{
    const int tid = threadIdx.x;
    const int wv = tid >> 6, lane = tid & 63;
    const int r = lane & 15, kg = lane >> 4;

    float betb[5];
#pragma unroll
    for (int n = 0; n < 5; ++n) betb[n] = bnl[n * 16 + r];
    asm volatile("" :: "v"(betb[0]), "v"(betb[1]), "v"(betb[2]),
                       "v"(betb[3]), "v"(betb[4]));

    f32x4 acc[4][5];
#pragma unroll
    for (int mm = 0; mm < 4; ++mm)
#pragma unroll
        for (int n = 0; n < 5; ++n) {
            f32x4 bi = {betb[n], betb[n], betb[n], betb[n]};
            acc[mm][n] = bi;
        }

    int aBase[4];
#pragma unroll
    for (int mm = 0; mm < 4; ++mm)
        aBase[mm] = inBase + ((wv * 4 + mm) * 18 + r) * 176 + kg * 16;

    auto stage = [&](int step) {
        const char* src = Wl + step * 15360;
        char* dst = sm + BB_OFF + (step % 3) * 16384;
        gload_lds16(src + tid * 16,          dst + tid * 16);           // [0,4096)
        gload_lds16(src + 4096 + tid * 16,   dst + 4096 + tid * 16);    // [4096,8192)
        gload_lds16(src + 8192 + tid * 16,   dst + 8192 + tid * 16);    // [8192,12288)
        gload_lds16(src + 11264 + tid * 16,  dst + 11264 + tid * 16);   // [11264,15360) overlap ok
    };

    asm volatile("s_waitcnt vmcnt(0)" ::: "memory");
    stage(0); stage(1);
    asm volatile("s_waitcnt vmcnt(4) lgkmcnt(0)" ::: "memory");
    __builtin_amdgcn_s_barrier();

#pragma unroll
    for (int s = 0; s < 9; ++s) {
        if (s + 2 < 9) stage(s + 2);
        const int dt = ((s / 3) * 18 + (s % 3)) * 176;
        const int sb = BB_OFF + (s % 3) * 16384;
#pragma unroll
        for (int kb = 0; kb < 3; ++kb) {
            short8 bf[5];
#pragma unroll
            for (int n = 0; n < 5; ++n)
                bf[n] = *(const short8*)(sm + sb + kb * 5120 + n * 1024 + lane * 16);
#pragma unroll
            for (int mm = 0; mm < 4; ++mm) {
                short8 af = *(const short8*)(sm + aBase[mm] + dt + kb * 64);
#pragma unroll
                for (int n = 0; n < 5; ++n)
                    acc[mm][n] = __builtin_amdgcn_mfma_f32_16x16x32_bf16(
                        af, bf[n], acc[mm][n], 0, 0, 0);
            }
        }
        if (s + 2 < 9)
            asm volatile("s_waitcnt vmcnt(4) lgkmcnt(0)" ::: "memory");
        else
            asm volatile("s_waitcnt vmcnt(0) lgkmcnt(0)" ::: "memory");
        __builtin_amdgcn_s_barrier();
    }

#pragma unroll
    for (int mm = 0; mm < 4; ++mm) {
        int y = wv * 4 + mm;
#pragma unroll
        for (int n = 0; n < 5; ++n) {
            int co = n * 16 + r;
#pragma unroll
            for (int j = 0; j < 4; ++j) {
                int x = kg * 4 + j;
                float o = fmaxf(acc[mm][n][j], 0.f);
                if (MODE == 1) {
                    Yreg[mm][n][j] = o;
                    *(bf16*)(sm + Z_OFF + ((y + 1) * 18 + x + 1) * 176 + co * 2) = f2b(o);
                } else {
                    float nv = Yreg[mm][n][j] + o;
                    Yreg[mm][n][j] = nv;
                    if (STOREZ)
                        *(bf16*)(sm + Z_OFF + ((y + 1) * 18 + x + 1) * 176 + co * 2) = f2b(nv);
                }
            }
        }
    }
}

// ---------------------------------------------------------------------------
__global__ __launch_bounds__(NT, 1) void refine_kernel(
    const int* __restrict__ sel,
    const float* __restrict__ hid, const float* __restrict__ pha,
    const char* __restrict__ Wf, const float* __restrict__ wlastT,
    const float* __restrict__ bnbeta, float* __restrict__ out)
{
    __shared__ __align__(16) char sm[SMEM_SZ];
    const int tid = threadIdx.x;
    const int p = blockIdx.x;
    const int e = sel[p];
    const int b = p >> 9;
    const int pi = e >> 6, pj = e & 63;

    // zero-fill LDS once (pad bytes / stale-data safety)
    {
        uint4 z4 = {0u, 0u, 0u, 0u};
        uint4* z = (uint4*)sm;
        for (int t = tid; t < SMEM_SZ / 16; t += NT) z[t] = z4;
    }
    __syncthreads();

    // gather X[576 pix][ch31] bf16, 80B rows
    const int r0 = pi * 16 - 4, c0 = pj * 16 - 4;
    for (int t = tid; t < 32 * 576; t += NT) {
        int c = t / 576, pix = t - c * 576;
        int gr = r0 + pix / 24, gc = c0 + pix % 24;
        float v = 0.f;
        if (c < 31 && (unsigned)gr < 1024u && (unsigned)gc < 1024u)
            v = (c < 30) ? hid[((b * 30 + c) * 1024 + gr) * 1024 + gc]
                         : pha[(b * 1024 + gr) * 1024 + gc];
        *(bf16*)(sm + X_OFF + pix * 80 + c * 2) = f2b(v);
    }
    // conv0 prologue (vmcnt(0)+lgkmcnt(0)+barrier) covers the gather.

    conv_small<24, 22, 1,  80, 160, 8>(sm, X_OFF,  A0_OFF, Wf,          bnbeta);
    conv_small<22, 20, 3, 160, 176, 7>(sm, A0_OFF, A1_OFF, Wf + 46080,  bnbeta + 80);
    conv_small<20, 18, 3, 176, 176, 6>(sm, A1_OFF, A2_OFF, Wf + 184320, bnbeta + 160);

    // zero Z-ring border (68 cells x 176B); published by pre3 prologue barrier
    for (int t = tid; t < 68 * 11; t += NT) {
        int cell = t / 11, part = t % 11;
        int i, j;
        if (cell < 18)      { i = 0;  j = cell; }
        else if (cell < 36) { i = 17; j = cell - 18; }
        else { int k = cell - 36; i = 1 + (k >> 1); j = (k & 1) ? 17 : 0; }
        *(uint4*)(sm + Z_OFF + (i * 18 + j) * 176 + part * 16) = (uint4){0u, 0u, 0u, 0u};
    }

    f32x4 Yreg[4][5];
    conv_big<1, 1>(sm, A2_OFF, Wf + 322560, bnbeta + 240, Yreg);
#pragma unroll 1
    for (int l = 0; l < 6; ++l)
        conv_big<2, 1>(sm, Z_OFF, Wf + 460800 + l * 138240, bnbeta + 320 + l * 80, Yreg);
    conv_big<2, 0>(sm, Z_OFF, Wf + 460800 + 6 * 138240, bnbeta + 800, Yreg);

    // spill Y trunk (f32, stride 336B) over dead A2/Z region
    {
        const int wv = tid >> 6, lane = tid & 63;
        const int r = lane & 15, kg = lane >> 4;
#pragma unroll
        for (int mm = 0; mm < 4; ++mm)
#pragma unroll
            for (int n = 0; n < 5; ++n) {
                int co = n * 16 + r;
#pragma unroll
                for (int j = 0; j < 4; ++j) {
                    int pix = (wv * 4 + mm) * 16 + kg * 4 + j;
                    *(float*)(sm + YF_OFF + pix * 336 + co * 4) = Yreg[mm][n][j];
                }
            }
    }
    __syncthreads();

    // last conv 80->1 SAME; 1 thread per pixel
    {
        int y = tid >> 4, x = tid & 15;
        float accv = 0.f;
        const float* Yb = (const float*)(sm + YF_OFF);
#pragma unroll
        for (int tap = 0; tap < 9; ++tap) {
            int iy = y + tap / 3 - 1, ix = x + tap % 3 - 1;
            if ((unsigned)iy >= 16u || (unsigned)ix >= 16u) continue;
            const float* yp = Yb + (iy * 16 + ix) * 84;
            const float* wp = wlastT + tap * 80;
            for (int c = 0; c < 80; c += 4) {
                float4 a  = *(const float4*)(yp + c);
                float4 w4 = *(const float4*)(wp + c);
                accv += a.x * w4.x + a.y * w4.y + a.z * w4.z + a.w * w4.w;
            }
        }
        out[b * 1048576 + (pi * 16 + y) * 1024 + pj * 16 + x] = accv;
    }
}

// ---------------------------------------------------------------------------
extern "C" void kernel_launch(void* const* d_in, const int* in_sizes, int n_in,
                              void* d_out, int out_size, void* d_ws, size_t ws_size,
                              hipStream_t stream)
{
    (void)in_sizes; (void)n_in; (void)out_size; (void)ws_size;
    const float* pha     = (const float*)d_in[0];
    const float* err     = (const float*)d_in[1];
    const float* hid     = (const float*)d_in[2];
    const float* w0      = (const float*)d_in[3];
    const float* bn0     = (const float*)d_in[4];
    const float* w_pre   = (const float*)d_in[5];
    const float* bn_pre  = (const float*)d_in[6];
    const float* w_post  = (const float*)d_in[7];
    const float* bn_post = (const float*)d_in[8];
    const float* w_last  = (const float*)d_in[9];
    float* out = (float*)d_out;

    char* ws = (char*)d_ws;
    bf16*  Wf     = (bf16*)ws;                 // 714240 bf16 = 1,428,480 B (+1KB stage-overread pad)
    float* wlastT = (float*)(ws + 1429504);    // 720 f32
    float* bnbeta = (float*)(ws + 1432384);    // 880 f32
    int*   sel    = (int*)(ws + 1441792);      // 1024 int

    hipLaunchKernelGGL(wt_kernel, dim3(2797), dim3(256), 0, stream,
                       w0, w_pre, w_post, w_last, bn0, bn_pre, bn_post,
                       Wf, wlastT, bnbeta);
    hipLaunchKernelGGL(topk_kernel, dim3(32), dim3(1024), 0, stream,
                       err, out + 2097152, sel);
    hipLaunchKernelGGL(copy_kernel, dim3(2048), dim3(256), 0, stream,
                       (const uint4*)pha, (uint4*)out, 524288);
    hipLaunchKernelGGL(refine_kernel, dim3(1024), dim3(NT), 0, stream,
                       sel, hid, pha, (const char*)Wf, wlastT, bnbeta, out);
}

// Round 16
// 479.104 us; speedup vs baseline: 2.4774x; 2.0527x over previous
//
#include <hip/hip_runtime.h>
#include <hip/hip_bf16.h>
#include <stdint.h>

typedef __hip_bfloat16 bf16;
typedef __attribute__((ext_vector_type(8))) short short8;
typedef __attribute__((ext_vector_type(4))) float f32x4;

__device__ __forceinline__ bf16 f2b(float x) { return __float2bfloat16(x); }

// ---- LDS map (bytes) ----
// conv0: X[77440,123520) -> A0[0,77440)
// pre1 : A0 -> A1[77440,147840)
// pre2 : A1 -> A2[0,57024)
// pre3 : A2 -> Z ring[57024,114048) (18x18x176)
// post : Z rw; B slots S0[0,46080) S1[114048,160128); betas[160128,162368)
// final: Yf32[0,86016)
#define A0_OFF 0
#define X_OFF  77440
#define A1_OFF 77440
#define A2_OFF 0
#define Z_OFF  57024
#define S0_OFF 0
#define S1_OFF 114048
#define PB_OFF 160128
#define YF_OFF 0
#define SMEM_SZ 163200

__device__ __forceinline__ void gload_lds16(const void* g, char* l) {
    __builtin_amdgcn_global_load_lds(
        (const __attribute__((address_space(1))) unsigned int*)g,
        (__attribute__((address_space(3))) unsigned int*)l, 16, 0, 0);
}

// ---------------------------------------------------------------------------
// Top-k: exact rank, jax tie-break (lower index wins). 32 blocks.
// ---------------------------------------------------------------------------
__global__ __launch_bounds__(1024) void topk_kernel(const float* __restrict__ err,
                                                    float* __restrict__ ref_out,
                                                    int* __restrict__ sel)
{
    __shared__ uint64_t keys[4096];
    const int b = blockIdx.x >> 4, slice = blockIdx.x & 15;
    const float* e = err + b * 4096;
    for (int t = threadIdx.x; t < 4096; t += 1024) {
        uint32_t u = __float_as_uint(e[t]);
        u ^= (u >> 31) ? 0xFFFFFFFFu : 0x80000000u;
        keys[t] = ((uint64_t)u << 32) | (uint32_t)(4095 - t);
    }
    __syncthreads();
    const int cand = slice * 256 + (threadIdx.x >> 2);
    const int part = threadIdx.x & 3;
    const uint64_t mykey = keys[cand];
    int r = 0;
#pragma unroll 8
    for (int j = part * 1024; j < part * 1024 + 1024; ++j)
        r += (keys[j] > mykey) ? 1 : 0;
    r += __shfl_xor(r, 1);
    r += __shfl_xor(r, 2);
    if (part == 0) {
        bool s = (r < 512);
        if (s) sel[b * 512 + r] = cand;
        ref_out[b * 4096 + cand] = (s && e[cand] > 0.f) ? 1.f : 0.f;
    }
}

// ---------------------------------------------------------------------------
// Weight prepack, BN inv folded in, zero-padded k>=C_in.
//  conv0 @0      : [tap][n][lane][8]              (23040 el)
//  pre1-3 @23040 : [l][tap][kb][n][lane][8]       (69120 el each)
//  post  @230400 : [l][kb][tap][n][lane][8] x7    (69120 el each, kb-major)
// ---------------------------------------------------------------------------
__global__ void wt_kernel(const float* __restrict__ w0, const float* __restrict__ wpre,
                          const float* __restrict__ wpost, const float* __restrict__ w_last,
                          const float* __restrict__ bn0, const float* __restrict__ bn_pre,
                          const float* __restrict__ bn_post,
                          bf16* __restrict__ Wf, float* __restrict__ wlastT,
                          float* __restrict__ bnbeta)
{
    int t = blockIdx.x * blockDim.x + threadIdx.x;
    if (t < 714240) {
        int l, tap, kb, rem;
        if (t < 23040) { l = 0; tap = t / 2560; kb = 0; rem = t % 2560; }
        else {
            int t2 = t - 23040;
            l = 1 + t2 / 69120;
            int r0 = t2 % 69120;
            if (l <= 3) {                       // pre layers: [tap][kb][n]
                tap = r0 / 7680;
                int r1 = r0 % 7680;
                kb = r1 / 2560; rem = r1 % 2560;
            } else {                            // post layers: [kb][tap][n]
                kb = r0 / 23040;
                int r1 = r0 % 23040;
                tap = r1 / 2560; rem = r1 % 2560;
            }
        }
        int n = rem / 512, r2 = rem % 512, lane = r2 / 8, i = r2 % 8;
        int co = n * 16 + (lane & 15);
        int k  = kb * 32 + (lane >> 4) * 8 + i;
        float v = 0.f;
        if (l == 0)      { if (k < 31) v = w0[(co * 31 + k) * 9 + tap]; }
        else if (l <= 3) { if (k < 80) v = wpre[(((l - 1) * 80 + co) * 80 + k) * 9 + tap]; }
        else             { if (k < 80) v = wpost[(((l - 4) * 80 + co) * 80 + k) * 9 + tap]; }
        const float* src = (l == 0) ? bn0 : (l <= 3 ? bn_pre + (l - 1) * 320
                                                    : bn_post + (l - 4) * 320);
        float inv = src[co] * rsqrtf(src[240 + co] + 1e-5f);
        Wf[t] = f2b(v * inv);
    } else if (t < 714960) {
        int i = t - 714240; int tap = i / 80, ci = i % 80;
        wlastT[tap * 80 + ci] = w_last[ci * 9 + tap];
    } else if (t < 715840) {
        int i = t - 714960; int l = i / 80, co = i % 80;
        const float* src = (l == 0) ? bn0 : (l <= 3 ? bn_pre + (l - 1) * 320
                                                    : bn_post + (l - 4) * 320);
        float inv = src[co] * rsqrtf(src[240 + co] + 1e-5f);
        bnbeta[i] = src[80 + co] - src[160 + co] * inv;
    }
}

// ---------------------------------------------------------------------------
__global__ void copy_kernel(const uint4* __restrict__ src, uint4* __restrict__ dst, int n)
{
    int t = blockIdx.x * blockDim.x + threadIdx.x;
    if (t < n) dst[t] = src[t];
}

// ---------------------------------------------------------------------------
// Pre layer (VALID conv): B fragments double-buffered in REGISTERS straight
// from global (L2/L3-resident) -> ZERO intra-layer barriers. One entry
// barrier publishes the previous layer's LDS writes.
// MODE 0: bf16 -> outBase; MODE 1 (pre3): Yreg = relu(acc), Z-ring store.
// ---------------------------------------------------------------------------
template <int NIN, int NOUT, int KB, int ISTR, int OSTR, int MODE, int BORDER>
__device__ __forceinline__ void conv_reg(char* sm, int inBase, int outBase,
                                         const char* __restrict__ Wl,
                                         const float* __restrict__ bnl,
                                         f32x4 (&Yreg)[2][5])
{
    const int tid = threadIdx.x;
    const int wv = tid >> 6, lane = tid & 63;
    const int r = lane & 15, kg = lane >> 4;
    constexpr int NPIX  = NOUT * NOUT;
    constexpr int NMT   = (NPIX + 15) / 16;
    constexpr int NSTEP = 9 * KB;
    constexpr int PMAX  = (NMT > 16) ? 2 : 1;

    asm volatile("s_waitcnt lgkmcnt(0)" ::: "memory");
    __builtin_amdgcn_s_barrier();

    if (BORDER) {   // zero Z-ring border (writes disjoint from A2 reads)
        for (int t = tid; t < 68 * 11; t += 512) {
            int cell = t / 11, part = t % 11;
            int i, j;
            if (cell < 18)      { i = 0;  j = cell; }
            else if (cell < 36) { i = 17; j = cell - 18; }
            else { int k = cell - 36; i = 1 + (k >> 1); j = (k & 1) ? 17 : 0; }
            *(uint4*)(sm + Z_OFF + (i * 18 + j) * 176 + part * 16) = (uint4){0u, 0u, 0u, 0u};
        }
    }

    int aA[PMAX][2];
    bool act[PMAX][2];
#pragma unroll
    for (int pp = 0; pp < PMAX; ++pp)
#pragma unroll
        for (int mm = 0; mm < 2; ++mm) {
            int mt = (wv + pp * 8) * 2 + mm;
            int pix = mt * 16 + r;
            act[pp][mm] = (mt < NMT);   // wave-uniform
            int cp = pix < NPIX ? pix : NPIX - 1;
            aA[pp][mm] = inBase + ((cp / NOUT) * NIN + cp % NOUT) * ISTR + kg * 16;
        }

    float betb[5];
#pragma unroll
    for (int n = 0; n < 5; ++n) betb[n] = bnl[n * 16 + r];

    f32x4 acc[PMAX][2][5];
#pragma unroll
    for (int pp = 0; pp < PMAX; ++pp)
#pragma unroll
        for (int mm = 0; mm < 2; ++mm)
#pragma unroll
            for (int n = 0; n < 5; ++n) {
                f32x4 bi = {betb[n], betb[n], betb[n], betb[n]};
                acc[pp][mm][n] = bi;
            }

    short8 B0[5], B1[5];
#pragma unroll
    for (int n = 0; n < 5; ++n)
        B0[n] = *(const short8*)(Wl + n * 1024 + lane * 16);

    auto body = [&](short8 (&Bc)[5], short8 (&Bn)[5], int s) {
        if (s + 1 < NSTEP) {
#pragma unroll
            for (int n = 0; n < 5; ++n)
                Bn[n] = *(const short8*)(Wl + (s + 1) * 5120 + n * 1024 + lane * 16);
        }
        const int tap = s / KB, kb = s % KB;
        const int dtap = (tap / 3) * NIN + (tap % 3);
#pragma unroll
        for (int pp = 0; pp < PMAX; ++pp)
#pragma unroll
            for (int mm = 0; mm < 2; ++mm) {
                if (!act[pp][mm]) continue;
                short8 af = *(const short8*)(sm + aA[pp][mm] + dtap * ISTR + kb * 64);
#pragma unroll
                for (int n = 0; n < 5; ++n)
                    acc[pp][mm][n] = __builtin_amdgcn_mfma_f32_16x16x32_bf16(
                        af, Bc[n], acc[pp][mm][n], 0, 0, 0);
            }
    };

#pragma unroll
    for (int s2 = 0; s2 < NSTEP; s2 += 2) {
        body(B0, B1, s2);
        if (s2 + 1 < NSTEP) body(B1, B0, s2 + 1);
    }

    // epilogue: writes disjoint from this layer's reads -> no barrier needed
#pragma unroll
    for (int pp = 0; pp < PMAX; ++pp)
#pragma unroll
        for (int mm = 0; mm < 2; ++mm) {
            int mt = (wv + pp * 8) * 2 + mm;
            if (act[pp][mm]) {
#pragma unroll
                for (int n = 0; n < 5; ++n) {
                    int co = n * 16 + r;
#pragma unroll
                    for (int j = 0; j < 4; ++j) {
                        int pix = mt * 16 + kg * 4 + j;
                        if (pix < NPIX) {
                            float o = fmaxf(acc[pp][mm][n][j], 0.f);
                            if (MODE == 0) {
                                *(bf16*)(sm + outBase + pix * OSTR + co * 2) = f2b(o);
                            } else {
                                Yreg[mm][n][j] = o;
                                int y = pix >> 4, x = pix & 15;
                                *(bf16*)(sm + Z_OFF + ((y + 1) * 18 + x + 1) * 176 + co * 2) = f2b(o);
                            }
                        }
                    }
                }
            }
        }
}

// stage one 46080B kb-chunk: 6 wave-uniform DMA instructions
__device__ __forceinline__ void post_stage(char* sm, const char* src, int slotOff, int tid)
{
    char* dst = sm + slotOff;
    gload_lds16(src + tid * 16,         dst + tid * 16);
    gload_lds16(src + 8192 + tid * 16,  dst + 8192 + tid * 16);
    gload_lds16(src + 16384 + tid * 16, dst + 16384 + tid * 16);
    gload_lds16(src + 24576 + tid * 16, dst + 24576 + tid * 16);
    gload_lds16(src + 32768 + tid * 16, dst + 32768 + tid * 16);
    gload_lds16(src + 37888 + tid * 16, dst + 37888 + tid * 16);   // overlap = same bytes
}

// ---------------------------------------------------------------------------
__global__ __launch_bounds__(512, 2) void refine_kernel(
    const int* __restrict__ sel,
    const float* __restrict__ hid, const float* __restrict__ pha,
    const char* __restrict__ Wf, const float* __restrict__ wlastT,
    const float* __restrict__ bnbeta, float* __restrict__ out)
{
    __shared__ __align__(16) char sm[SMEM_SZ];
    const int tid = threadIdx.x;
    const int p = blockIdx.x;
    const int e = sel[p];
    const int b = p >> 9;
    const int pi = e >> 6, pj = e & 63;

    // zero-fill LDS once (stale-data safety)
    {
        uint4 z4 = {0u, 0u, 0u, 0u};
        uint4* z = (uint4*)sm;
        for (int t = tid; t < SMEM_SZ / 16; t += 512) z[t] = z4;
    }
    __syncthreads();

    // gather X[576 pix][ch31] bf16 (80B rows) + copy post betas to LDS
    const int r0 = pi * 16 - 4, c0 = pj * 16 - 4;
    for (int t = tid; t < 32 * 576; t += 512) {
        int c = t / 576, pix = t - c * 576;
        int gr = r0 + pix / 24, gc = c0 + pix % 24;
        float v = 0.f;
        if (c < 31 && (unsigned)gr < 1024u && (unsigned)gc < 1024u)
            v = (c < 30) ? hid[((b * 30 + c) * 1024 + gr) * 1024 + gc]
                         : pha[(b * 1024 + gr) * 1024 + gc];
        *(bf16*)(sm + X_OFF + pix * 80 + c * 2) = f2b(v);
    }
    for (int t = tid; t < 560; t += 512)
        ((float*)(sm + PB_OFF))[t] = bnbeta[320 + t];   // post betas (l=4..10)

    f32x4 Yreg[2][5];

    conv_reg<24, 22, 1,  80, 160, 0, 0>(sm, X_OFF,  A0_OFF, Wf,           bnbeta,       Yreg);
    conv_reg<22, 20, 3, 160, 176, 0, 0>(sm, A0_OFF, A1_OFF, Wf + 46080,   bnbeta + 80,  Yreg);
    conv_reg<20, 18, 3, 176, 176, 0, 0>(sm, A1_OFF, A2_OFF, Wf + 184320,  bnbeta + 160, Yreg);
    conv_reg<18, 16, 3, 176, 176, 1, 1>(sm, A2_OFF, 0,      Wf + 322560,  bnbeta + 240, Yreg);

    // ---- post: 7 layers, kb-major chunks, 2 slots, WAIT-THEN-BARRIER ----
    {
        const int wv = tid >> 6, lane = tid & 63;
        const int r = lane & 15, kg = lane >> 4;
        const char* postW = Wf + 460800;
        const float* ldsBeta = (const float*)(sm + PB_OFF);

        int aBase[2];
#pragma unroll
        for (int mm = 0; mm < 2; ++mm)
            aBase[mm] = Z_OFF + ((2 * wv + mm) * 18 + r) * 176 + kg * 16;

        // prologue: pre3 done everywhere (A2 dead, Z visible); stage chunk 0;
        // full drain BEFORE barrier -> chunk 0 globally complete at exit.
        asm volatile("s_waitcnt lgkmcnt(0)" ::: "memory");
        __builtin_amdgcn_s_barrier();
        post_stage(sm, postW, S0_OFF, tid);
        asm volatile("s_waitcnt vmcnt(0) lgkmcnt(0)" ::: "memory");
        __builtin_amdgcn_s_barrier();

#pragma unroll 1
        for (int l = 0; l < 7; ++l) {
            float betb[5];
#pragma unroll
            for (int n = 0; n < 5; ++n) betb[n] = ldsBeta[l * 80 + n * 16 + r];
            f32x4 acc[2][5];
#pragma unroll
            for (int mm = 0; mm < 2; ++mm)
#pragma unroll
                for (int n = 0; n < 5; ++n) {
                    f32x4 bi = {betb[n], betb[n], betb[n], betb[n]};
                    acc[mm][n] = bi;
                }

#pragma unroll
            for (int k = 0; k < 3; ++k) {
                const int g = l * 3 + k;
                // stage next chunk into slot (g+1)&1: its previous occupant
                // (chunk g-1) was read-complete at the previous barrier.
                if (g < 20)
                    post_stage(sm, postW + (g + 1) * 46080,
                               ((g + 1) & 1) ? S1_OFF : S0_OFF, tid);
                const int slot = (g & 1) ? S1_OFF : S0_OFF;
                const int aK0 = aBase[0] + k * 64, aK1 = aBase[1] + k * 64;
#pragma unroll
                for (int tap = 0; tap < 9; ++tap) {
                    const int dt = ((tap / 3) * 18 + (tap % 3)) * 176;
                    short8 bfv[5];
#pragma unroll
                    for (int n = 0; n < 5; ++n)
                        bfv[n] = *(const short8*)(sm + slot + tap * 5120 + n * 1024 + lane * 16);
                    short8 af0 = *(const short8*)(sm + aK0 + dt);
                    short8 af1 = *(const short8*)(sm + aK1 + dt);
#pragma unroll
                    for (int n = 0; n < 5; ++n)
                        acc[0][n] = __builtin_amdgcn_mfma_f32_16x16x32_bf16(
                            af0, bfv[n], acc[0][n], 0, 0, 0);
#pragma unroll
                    for (int n = 0; n < 5; ++n)
                        acc[1][n] = __builtin_amdgcn_mfma_f32_16x16x32_bf16(
                            af1, bfv[n], acc[1][n], 0, 0, 0);
                }
                // WAIT-THEN-BARRIER: next chunk complete + this slot's reads
                // done on ALL waves at barrier exit.
                asm volatile("s_waitcnt vmcnt(0) lgkmcnt(0)" ::: "memory");
                __builtin_amdgcn_s_barrier();
            }

            // residual update; Z rewrite safe (all reads done at last barrier)
#pragma unroll
            for (int mm = 0; mm < 2; ++mm) {
                int y = 2 * wv + mm;
#pragma unroll
                for (int n = 0; n < 5; ++n) {
                    int co = n * 16 + r;
#pragma unroll
                    for (int j = 0; j < 4; ++j) {
                        int x = kg * 4 + j;
                        float o = fmaxf(acc[mm][n][j], 0.f);
                        float nv = Yreg[mm][n][j] + o;
                        Yreg[mm][n][j] = nv;
                        if (l < 6)
                            *(bf16*)(sm + Z_OFF + ((y + 1) * 18 + x + 1) * 176 + co * 2) = f2b(nv);
                    }
                }
            }
            if (l < 6) {   // publish Z before next layer reads it
                asm volatile("s_waitcnt lgkmcnt(0)" ::: "memory");
                __builtin_amdgcn_s_barrier();
            }
        }
    }

    // spill Y trunk (f32, stride 336B) over dead S0/Z region
    __syncthreads();
    {
        const int wv = tid >> 6, lane = tid & 63;
        const int r = lane & 15, kg = lane >> 4;
#pragma unroll
        for (int mm = 0; mm < 2; ++mm) {
            int mt = 2 * wv + mm;
#pragma unroll
            for (int n = 0; n < 5; ++n) {
                int co = n * 16 + r;
#pragma unroll
                for (int j = 0; j < 4; ++j) {
                    int pix = mt * 16 + kg * 4 + j;
                    *(float*)(sm + YF_OFF + pix * 336 + co * 4) = Yreg[mm][n][j];
                }
            }
        }
    }
    __syncthreads();

    // last conv 80->1 SAME; 2 threads per pixel
    {
        int pix = tid >> 1, half = tid & 1;
        int y = pix >> 4, x = pix & 15;
        float accv = 0.f;
        const float* Yb = (const float*)(sm + YF_OFF);
#pragma unroll
        for (int tap = 0; tap < 9; ++tap) {
            int iy = y + tap / 3 - 1, ix = x + tap % 3 - 1;
            if ((unsigned)iy >= 16u || (unsigned)ix >= 16u) continue;
            const float* yp = Yb + (iy * 16 + ix) * 84;
            const float* wp = wlastT + tap * 80;
            for (int c = half * 40; c < half * 40 + 40; c += 4) {
                float4 a  = *(const float4*)(yp + c);
                float4 w4 = *(const float4*)(wp + c);
                accv += a.x * w4.x + a.y * w4.y + a.z * w4.z + a.w * w4.w;
            }
        }
        accv += __shfl_xor(accv, 1);
        if (half == 0)
            out[b * 1048576 + (pi * 16 + y) * 1024 + pj * 16 + x] = accv;
    }
}

// ---------------------------------------------------------------------------
extern "C" void kernel_launch(void* const* d_in, const int* in_sizes, int n_in,
                              void* d_out, int out_size, void* d_ws, size_t ws_size,
                              hipStream_t stream)
{
    (void)in_sizes; (void)n_in; (void)out_size; (void)ws_size;
    const float* pha     = (const float*)d_in[0];
    const float* err     = (const float*)d_in[1];
    const float* hid     = (const float*)d_in[2];
    const float* w0      = (const float*)d_in[3];
    const float* bn0     = (const float*)d_in[4];
    const float* w_pre   = (const float*)d_in[5];
    const float* bn_pre  = (const float*)d_in[6];
    const float* w_post  = (const float*)d_in[7];
    const float* bn_post = (const float*)d_in[8];
    const float* w_last  = (const float*)d_in[9];
    float* out = (float*)d_out;

    char* ws = (char*)d_ws;
    bf16*  Wf     = (bf16*)ws;                 // 714240 bf16 = 1,428,480 B
    float* wlastT = (float*)(ws + 1429504);    // 720 f32
    float* bnbeta = (float*)(ws + 1432384);    // 880 f32
    int*   sel    = (int*)(ws + 1441792);      // 1024 int

    hipLaunchKernelGGL(wt_kernel, dim3(2797), dim3(256), 0, stream,
                       w0, w_pre, w_post, w_last, bn0, bn_pre, bn_post,
                       Wf, wlastT, bnbeta);
    hipLaunchKernelGGL(topk_kernel, dim3(32), dim3(1024), 0, stream,
                       err, out + 2097152, sel);
    hipLaunchKernelGGL(copy_kernel, dim3(2048), dim3(256), 0, stream,
                       (const uint4*)pha, (uint4*)out, 524288);
    hipLaunchKernelGGL(refine_kernel, dim3(1024), dim3(512), 0, stream,
                       sel, hid, pha, (const char*)Wf, wlastT, bnbeta, out);
}